// Round 9
// baseline (835.342 us; speedup 1.0000x reference)
//
#include <hip/hip_runtime.h>
#include <math.h>

#define BB 2
#define TT 2048
#define DD 2048
#define HH 16
#define KK 128

typedef _Float16 h4 __attribute__((ext_vector_type(4)));
typedef _Float16 v8h __attribute__((ext_vector_type(8)));
typedef float v4f __attribute__((ext_vector_type(4)));

// ---------------------------------------------------------------------------
// FALLBACK fp32 GEMM — used only if ws is too small for the f16 buffers.
// ---------------------------------------------------------------------------
__global__ __launch_bounds__(256) void gemm_nt3(const float* __restrict__ A,
                                                const float* __restrict__ W0,
                                                const float* __restrict__ W1,
                                                const float* __restrict__ W2,
                                                float* __restrict__ Cbase,
                                                int M, int N, int Kd) {
  __shared__ float As[8][128];
  __shared__ float Bs[8][128];
  const int z = blockIdx.z;
  const float* W = (z == 0) ? W0 : (z == 1) ? W1 : W2;
  float* C = Cbase + (size_t)z * M * N;
  const int tid = threadIdx.x;
  const int bm = blockIdx.y * 128;
  const int bn = blockIdx.x * 128;
  const int lrow = tid >> 1;
  const int lcol = (tid & 1) * 4;
  const int rm = (tid >> 4) * 8;
  const int rn = (tid & 15) * 8;
  const float* Ap = A + (size_t)(bm + lrow) * Kd + lcol;
  const float* Wp = W + (size_t)(bn + lrow) * Kd + lcol;
  float acc[8][8];
#pragma unroll
  for (int i = 0; i < 8; i++)
#pragma unroll
    for (int j = 0; j < 8; j++) acc[i][j] = 0.f;
  float4 av = *(const float4*)Ap;
  float4 wv = *(const float4*)Wp;
  for (int d0 = 0; d0 < Kd; d0 += 8) {
    __syncthreads();
    As[lcol + 0][lrow] = av.x; As[lcol + 1][lrow] = av.y;
    As[lcol + 2][lrow] = av.z; As[lcol + 3][lrow] = av.w;
    Bs[lcol + 0][lrow] = wv.x; Bs[lcol + 1][lrow] = wv.y;
    Bs[lcol + 2][lrow] = wv.z; Bs[lcol + 3][lrow] = wv.w;
    __syncthreads();
    if (d0 + 8 < Kd) {
      av = *(const float4*)(Ap + d0 + 8);
      wv = *(const float4*)(Wp + d0 + 8);
    }
#pragma unroll
    for (int kk = 0; kk < 8; kk++) {
      const float4 a0 = *(const float4*)&As[kk][rm];
      const float4 a1 = *(const float4*)&As[kk][rm + 4];
      const float4 b0 = *(const float4*)&Bs[kk][rn];
      const float4 b1 = *(const float4*)&Bs[kk][rn + 4];
      const float ar[8] = {a0.x, a0.y, a0.z, a0.w, a1.x, a1.y, a1.z, a1.w};
      const float br[8] = {b0.x, b0.y, b0.z, b0.w, b1.x, b1.y, b1.z, b1.w};
#pragma unroll
      for (int i = 0; i < 8; i++)
#pragma unroll
        for (int j = 0; j < 8; j++) acc[i][j] = fmaf(ar[i], br[j], acc[i][j]);
    }
  }
#pragma unroll
  for (int i = 0; i < 8; i++) {
    float* cp = C + (size_t)(bm + rm + i) * N + bn + rn;
    float4 c0 = {acc[i][0], acc[i][1], acc[i][2], acc[i][3]};
    float4 c1 = {acc[i][4], acc[i][5], acc[i][6], acc[i][7]};
    *(float4*)cp = c0;
    *(float4*)(cp + 4) = c1;
  }
}

// ---------------------------------------------------------------------------
// Convert: x -> xh + xl (f16 hi/lo split), Wq/Wk/Wv -> Wf (single f16).
// ---------------------------------------------------------------------------
__global__ __launch_bounds__(256) void convert_f16(
    const float* __restrict__ x, const float* __restrict__ Wq,
    const float* __restrict__ Wk, const float* __restrict__ Wv,
    _Float16* __restrict__ xh, _Float16* __restrict__ xl,
    _Float16* __restrict__ Wf) {
  const size_t N4X = (size_t)BB * TT * DD / 4;
  const size_t N4W = (size_t)(HH * KK) * DD / 4;
  const size_t i = (size_t)blockIdx.x * 256 + threadIdx.x;
  if (i < N4X) {
    const float4 v = ((const float4*)x)[i];
    h4 hi, lo;
    hi.x = (_Float16)v.x; hi.y = (_Float16)v.y;
    hi.z = (_Float16)v.z; hi.w = (_Float16)v.w;
    lo.x = (_Float16)(v.x - (float)hi.x);
    lo.y = (_Float16)(v.y - (float)hi.y);
    lo.z = (_Float16)(v.z - (float)hi.z);
    lo.w = (_Float16)(v.w - (float)hi.w);
    ((h4*)xh)[i] = hi;
    ((h4*)xl)[i] = lo;
  } else {
    const size_t j = i - N4X;
    const float* Ws = (j < N4W) ? Wq : (j < 2 * N4W) ? Wk : Wv;
    const size_t jj = (j < N4W) ? j : (j < 2 * N4W) ? (j - N4W) : (j - 2 * N4W);
    const float4 v = ((const float4*)Ws)[jj];
    h4 hi;
    hi.x = (_Float16)v.x; hi.y = (_Float16)v.y;
    hi.z = (_Float16)v.z; hi.w = (_Float16)v.w;
    ((h4*)Wf)[j] = hi;
  }
}

// ---------------------------------------------------------------------------
// MFMA GEMM: C[z] = xh*W[z]^T + xl*W[z]^T  (f16 in, fp32 out) — m97 structure
// ---------------------------------------------------------------------------
#define GLDS(gp, lp)                                              \
  __builtin_amdgcn_global_load_lds(                               \
      (const __attribute__((address_space(1))) void*)(gp),        \
      (__attribute__((address_space(3))) void*)(lp), 16, 0, 0)
#define GLDS4(gp, lp)                                             \
  __builtin_amdgcn_global_load_lds(                               \
      (const __attribute__((address_space(1))) void*)(gp),        \
      (__attribute__((address_space(3))) void*)(lp), 4, 0, 0)

__global__ __launch_bounds__(256) void gemm_mfma(
    const _Float16* __restrict__ xh, const _Float16* __restrict__ xl,
    const _Float16* __restrict__ Wf, float* __restrict__ Cbase) {
  __shared__ float4 lraw[1536];  // 24 KB = Ah | Al | Bs
  _Float16* Ah = (_Float16*)lraw;
  _Float16* Al = Ah + 4096;
  _Float16* Bs = Al + 4096;

  const int z = blockIdx.z;
  const _Float16* W = Wf + (size_t)z * DD * (HH * KK);
  float* C = Cbase + (size_t)z * (BB * TT) * (HH * KK);

  const int tid = threadIdx.x;
  const int w = tid >> 6;
  const int lane = tid & 63;
  const int bm = blockIdx.y * 128;
  const int bn = blockIdx.x * 128;
  const int wm = (w & 1) * 64;
  const int wn = (w >> 1) * 64;
  const int m16 = lane & 15;
  const int quad = lane >> 4;

  const _Float16* gAh = xh + (size_t)(bm + (tid >> 2)) * DD + (tid & 3) * 8;
  const _Float16* gAl = xl + (size_t)(bm + (tid >> 2)) * DD + (tid & 3) * 8;
  const _Float16* gB = W + (size_t)(bn + (tid >> 2)) * DD + (tid & 3) * 8;
  const int lb = w * 512;

  v4f acc[4][4];
#pragma unroll
  for (int i = 0; i < 4; i++)
#pragma unroll
    for (int j = 0; j < 4; j++) acc[i][j] = (v4f){0.f, 0.f, 0.f, 0.f};

  for (int d0 = 0; d0 < DD; d0 += 32) {
    GLDS(gAh + d0, Ah + lb);
    GLDS(gAh + d0 + 64 * DD, Ah + 2048 + lb);
    GLDS(gAl + d0, Al + lb);
    GLDS(gAl + d0 + 64 * DD, Al + 2048 + lb);
    GLDS(gB + d0, Bs + lb);
    GLDS(gB + d0 + 64 * DD, Bs + 2048 + lb);
    __syncthreads();
    v8h ah[4], al[4], bw[4];
#pragma unroll
    for (int i = 0; i < 4; i++) {
      ah[i] = *(const v8h*)&Ah[(wm + i * 16 + m16) * 32 + quad * 8];
      al[i] = *(const v8h*)&Al[(wm + i * 16 + m16) * 32 + quad * 8];
      bw[i] = *(const v8h*)&Bs[(wn + i * 16 + m16) * 32 + quad * 8];
    }
#pragma unroll
    for (int mi = 0; mi < 4; mi++)
#pragma unroll
      for (int ni = 0; ni < 4; ni++) {
        acc[mi][ni] = __builtin_amdgcn_mfma_f32_16x16x32_f16(ah[mi], bw[ni],
                                                             acc[mi][ni], 0, 0, 0);
        acc[mi][ni] = __builtin_amdgcn_mfma_f32_16x16x32_f16(al[mi], bw[ni],
                                                             acc[mi][ni], 0, 0, 0);
      }
    __syncthreads();
  }
#pragma unroll
  for (int mi = 0; mi < 4; mi++) {
#pragma unroll
    for (int r = 0; r < 4; r++) {
      float* cp =
          C + (size_t)(bm + wm + mi * 16 + quad * 4 + r) * (HH * KK) + bn + wn + m16;
#pragma unroll
      for (int ni = 0; ni < 4; ni++) cp[ni * 16] = acc[mi][ni][r];
    }
  }
}

// ---------------------------------------------------------------------------
// alpha/beta projections (unchanged)
// ---------------------------------------------------------------------------
__global__ __launch_bounds__(64) void ab_proj(const float* __restrict__ x,
                                              const float* __restrict__ Wa,
                                              const float* __restrict__ ba,
                                              const float* __restrict__ Wb,
                                              const float* __restrict__ bb,
                                              float* __restrict__ abq) {
  const int row = blockIdx.x;
  const int g = blockIdx.y;
  const int h0 = (g & 1) * 8;
  const bool isA = (g < 2);
  const float* W = isA ? Wa : Wb;
  const int lane = threadIdx.x;
  const float* xr = x + (size_t)row * DD;
  float acc[8];
#pragma unroll
  for (int j = 0; j < 8; j++) acc[j] = 0.f;
  for (int d = lane; d < DD; d += 64) {
    const float xv = xr[d];
#pragma unroll
    for (int j = 0; j < 8; j++)
      acc[j] = fmaf(xv, W[(size_t)(h0 + j) * DD + d], acc[j]);
  }
#pragma unroll
  for (int j = 0; j < 8; j++) {
#pragma unroll
    for (int off = 32; off > 0; off >>= 1) acc[j] += __shfl_xor(acc[j], off, 64);
  }
  if (lane == 0) {
    if (isA) {
#pragma unroll
      for (int j = 0; j < 8; j++) {
        const float z = acc[j] + ba[h0 + j];
        abq[((size_t)row * HH + h0 + j) * 4 + 0] = 1.0f / (1.0f + expf(-z));
      }
    } else {
#pragma unroll
      for (int j = 0; j < 8; j++) {
        const float z = acc[j] + bb[h0 + j];
        const float sp = (z > 20.f) ? z : log1pf(expf(z));
        abq[((size_t)row * HH + h0 + j) * 4 + 1] = sp * 0.08838834764831845f;
      }
    }
  }
}

// ---------------------------------------------------------------------------
// norm_pack: l2-normalize q,k; round to f16; write packed [k(128)|q(128)] f16
// per (b,t,h); kq-dot from the ROUNDED values -> abq slot 2 (r7-proven).
// ---------------------------------------------------------------------------
__global__ __launch_bounds__(256) void norm_pack(const float* __restrict__ q,
                                                 const float* __restrict__ k,
                                                 _Float16* __restrict__ kq,
                                                 float* __restrict__ abq) {
  const int vec = blockIdx.x * 4 + (threadIdx.x >> 6);
  const int l = threadIdx.x & 63;
  const float* qp = q + (size_t)vec * 128;
  const float* kp = k + (size_t)vec * 128;
  float q0 = qp[l], q1 = qp[l + 64];
  float k0 = kp[l], k1 = kp[l + 64];
  float sq = q0 * q0 + q1 * q1;
  float sk = k0 * k0 + k1 * k1;
#pragma unroll
  for (int off = 32; off > 0; off >>= 1) {
    sq += __shfl_xor(sq, off, 64);
    sk += __shfl_xor(sk, off, 64);
  }
  const float iq = 1.0f / fmaxf(sqrtf(sq), 1e-12f);
  const float ik = 1.0f / fmaxf(sqrtf(sk), 1e-12f);
  const _Float16 hq0 = (_Float16)(q0 * iq), hq1 = (_Float16)(q1 * iq);
  const _Float16 hk0 = (_Float16)(k0 * ik), hk1 = (_Float16)(k1 * ik);
  _Float16* kv = kq + (size_t)vec * 256;
  kv[l] = hk0;
  kv[l + 64] = hk1;
  kv[l + 128] = hq0;
  kv[l + 192] = hq1;
  float pq = (float)hq0 * (float)hk0 + (float)hq1 * (float)hk1;
#pragma unroll
  for (int off = 32; off > 0; off >>= 1) pq += __shfl_xor(pq, off, 64);
  if (l == 0) abq[(size_t)vec * 4 + 2] = pq;
}

// ---------------------------------------------------------------------------
// Scan v7: LDS-ring pipeline + f16 packed kq.
// r8 diagnosis: LDS pipe-bound — 16 stride-32B kq b128/CU-step at 4-way
// conflict (3.36e7 SQ_LDS_BANK_CONFLICT). Fix: kq staged as packed f16
// (512 B/step); lane g reads ALL its 8 k in ONE b128 at g*16 (stride-16,
// conflict-free), same for q -> kq reads 4x fewer, conflicts 0.
// v transposed per slot [row16][step8] (broadcast, conflict-free).
// Ring 4 slots x 8 steps; staging 7 GLDS/window (<=2 per wave); sync =
// raw s_barrier + vmcnt(8) exactly as r8 (8 newest = prior window stores).
// Math: v_fma_mix from f16 (r7-proven, absmax 9.8e-4).
// ---------------------------------------------------------------------------
#define DPP_ADD(x, ctrl)                                                     \
  ((x) + __int_as_float(__builtin_amdgcn_update_dpp(                         \
             0, __float_as_int(x), (ctrl), 0xF, 0xF, true)))

#define WSTEPS 8
#define NWIN (TT / WSTEPS)  // 256
#define VB 16384            // v ring base (after 4*8*512 kq ring)
#define ABB 18432           // ab ring base (after 4*512 v ring)

struct Slot {
  v8h kh, qh;
  float4 ab;
  float vv;
};

__global__ __launch_bounds__(256) void scan_kernel(
    const _Float16* __restrict__ kq, const float* __restrict__ v,
    const float* __restrict__ abq, float* __restrict__ o) {
  __shared__ __attribute__((aligned(16))) char lds[18944];
  const int bid = blockIdx.x;  // = s*32 + bh (V-splits of a bh share an XCD)
  const int bh = bid & 31;
  const int s = bid >> 5;  // 0..7
  const int h = bh & 15;
  const int b = bh >> 4;
  const int tid = threadIdx.x;
  const int w = tid >> 6;
  const int lane = tid & 63;
  const int rg = lane >> 4;       // 0..3 row within wave
  const int g = lane & 15;        // 0..15 column group (8 cols each)
  const int rowloc = w * 4 + rg;  // 0..15 row within block
  const int vrow = s * 16 + rowloc;

  float* ob = o + (size_t)b * TT * 2048 + (size_t)h * KK + vrow;

  // ---- staging: 7 GLDS per window, <=2 per wave ----
  auto stage = [&](int Wst) {
    const int t0 = Wst * WSTEPS;
    const int slot = Wst & 3;
#pragma unroll
    for (int i = 0; i < 2; i++) {
      const int id = w * 2 + i;
      if (id < 4) {  // kq: steps t0+2id (lanes<32) / t0+2id+1 (lanes>=32)
        const int t = t0 + 2 * id + (lane >> 5);
        const _Float16* src =
            kq + ((size_t)(b * TT + t) * HH + h) * 256 + (size_t)(lane & 31) * 8;
        GLDS(src, lds + slot * 4096 + id * 1024);
      } else if (id < 6) {  // v rows 8n..8n+7 x 8 steps, layout [row][step]
        const int n = id - 4;
        const float* src = v +
                           (size_t)(b * TT + t0 + (lane & 7)) * 2048 + h * 128 +
                           s * 16 + 8 * n + (lane >> 3);
        GLDS4(src, lds + VB + slot * 512 + n * 256);
      } else if (id == 6) {  // ab: 8 steps x 16 B
        if (lane < 8) {
          const float* src = abq + ((size_t)(b * TT + t0 + lane) * HH + h) * 4;
          GLDS(src, lds + ABB + slot * 128);
        }
      }
    }
  };

#define LOAD_SLOT(S_, t_)                                                   \
  {                                                                         \
    const int _sl = ((t_) >> 3) & 3;                                        \
    const int _j = (t_) & 7;                                                \
    const char* _sb = lds + _sl * 4096 + _j * 512;                          \
    S_.kh = *(const v8h*)(_sb + g * 16);                                    \
    S_.qh = *(const v8h*)(_sb + 256 + g * 16);                              \
    S_.vv = *(const float*)(lds + VB + _sl * 512 + rowloc * 32 + _j * 4);   \
    S_.ab = *(const float4*)(lds + ABB + _sl * 128 + _j * 16);              \
  }

#define STEP(S_, t_)                                                        \
  {                                                                         \
    const v8h kh = S_.kh;                                                   \
    const v8h qh = S_.qh;                                                   \
    float dkA = fmaf((float)kh[1], S1, (float)kh[0] * S0);                  \
    dkA = fmaf((float)kh[2], S2, dkA);                                      \
    dkA = fmaf((float)kh[3], S3, dkA);                                      \
    float dkB = fmaf((float)kh[5], S5, (float)kh[4] * S4);                  \
    dkB = fmaf((float)kh[6], S6, dkB);                                      \
    dkB = fmaf((float)kh[7], S7, dkB);                                      \
    float dqA = fmaf((float)qh[1], S1, (float)qh[0] * S0);                  \
    dqA = fmaf((float)qh[2], S2, dqA);                                      \
    dqA = fmaf((float)qh[3], S3, dqA);                                      \
    float dqB = fmaf((float)qh[5], S5, (float)qh[4] * S4);                  \
    dqB = fmaf((float)qh[6], S6, dqB);                                      \
    dqB = fmaf((float)qh[7], S7, dqB);                                      \
    float dk = dkA + dkB, dq = dqA + dqB;                                   \
    dk = DPP_ADD(dk, 0xB1);  dq = DPP_ADD(dq, 0xB1);                        \
    dk = DPP_ADD(dk, 0x4E);  dq = DPP_ADD(dq, 0x4E);                        \
    dk = DPP_ADD(dk, 0x141); dq = DPP_ADD(dq, 0x141);                       \
    dk = DPP_ADD(dk, 0x140); dq = DPP_ADD(dq, 0x140);                       \
    const float a_ = S_.ab.x, b_ = S_.ab.y, kqd = S_.ab.z;                  \
    const float u = b_ * (S_.vv - a_ * dk);                                 \
    const float oo = fmaf(a_, dq, u * kqd);                                 \
    S0 = fmaf(a_, S0, u * (float)kh[0]);                                    \
    S1 = fmaf(a_, S1, u * (float)kh[1]);                                    \
    S2 = fmaf(a_, S2, u * (float)kh[2]);                                    \
    S3 = fmaf(a_, S3, u * (float)kh[3]);                                    \
    S4 = fmaf(a_, S4, u * (float)kh[4]);                                    \
    S5 = fmaf(a_, S5, u * (float)kh[5]);                                    \
    S6 = fmaf(a_, S6, u * (float)kh[6]);                                    \
    S7 = fmaf(a_, S7, u * (float)kh[7]);                                    \
    if (g == 0) ob[(size_t)(t_) * 2048] = oo;                               \
  }

  // prologue: stage windows 0,1; drain; barrier; prime register pipeline
  stage(0);
  stage(1);
  __builtin_amdgcn_s_waitcnt(0x0F70);  // vmcnt(0)
  __builtin_amdgcn_s_barrier();

  Slot slA, slB;
  LOAD_SLOT(slA, 0);
  LOAD_SLOT(slB, 1);

  float S0 = 0.f, S1 = 0.f, S2 = 0.f, S3 = 0.f;
  float S4 = 0.f, S5 = 0.f, S6 = 0.f, S7 = 0.f;

  for (int W = 0; W < NWIN; W++) {
    if (W >= 1) {
      // per wave FIFO (old->new): [... , stage(W+1) (<=2), stores W-1 (8)]
      __builtin_amdgcn_s_waitcnt(0x0F78);  // vmcnt(8) -> stage(W+1) retired
      __builtin_amdgcn_s_barrier();
    }
    if (W + 2 < NWIN) stage(W + 2);
    const int t0 = W * WSTEPS;
#pragma unroll
    for (int j = 0; j < WSTEPS; j += 2) {
      const int t = t0 + j;
      STEP(slA, t);
      {
        const int tp = (t + 2 < TT) ? t + 2 : t;  // clamp; reread harmless
        LOAD_SLOT(slA, tp);
      }
      __builtin_amdgcn_sched_barrier(0);
      STEP(slB, t + 1);
      {
        const int tp = (t + 3 < TT) ? t + 3 : t;
        LOAD_SLOT(slB, tp);
      }
      __builtin_amdgcn_sched_barrier(0);
    }
  }
}

// ---------------------------------------------------------------------------
extern "C" void kernel_launch(void* const* d_in, const int* in_sizes, int n_in,
                              void* d_out, int out_size, void* d_ws,
                              size_t ws_size, hipStream_t stream) {
  const float* x = (const float*)d_in[0];
  const float* Wq = (const float*)d_in[1];
  const float* Wk = (const float*)d_in[2];
  const float* Wv = (const float*)d_in[3];
  const float* Wa = (const float*)d_in[4];
  const float* ba = (const float*)d_in[5];
  const float* Wb = (const float*)d_in[6];
  const float* bb = (const float*)d_in[7];
  float* out = (float*)d_out;
  float* ws = (float*)d_ws;

  const size_t PROJ = (size_t)BB * TT * HH * KK;  // 8,388,608
  const size_t NABQ = (size_t)BB * TT * HH * 4;
  float* qw = ws;
  float* kw = ws + PROJ;
  float* vw = ws + 2 * PROJ;
  float* abq = ws + 3 * PROJ;
  _Float16* xh = (_Float16*)(abq + NABQ);
  _Float16* xl = xh + (size_t)BB * TT * DD;
  _Float16* Wf = xl + (size_t)BB * TT * DD;
  const size_t NEED = (3 * PROJ + NABQ) * 4 +
                      ((size_t)BB * TT * DD * 2 + 3 * (size_t)(HH * KK) * DD) * 2;

  const int M = BB * TT;  // 4096
  const int N = HH * KK;  // 2048
  _Float16* kqf16;
  if (ws_size >= NEED) {
    const int cgrid = (int)(((size_t)BB * TT * DD / 4 + 3 * (size_t)N * DD / 4) / 256);
    convert_f16<<<cgrid, 256, 0, stream>>>(x, Wq, Wk, Wv, xh, xl, Wf);
    gemm_mfma<<<dim3(N / 128, M / 128, 3), 256, 0, stream>>>(xh, xl, Wf, qw);
    kqf16 = xh;  // xh/xl dead after gemm_mfma; reuse for packed kq
  } else {
    gemm_nt3<<<dim3(N / 128, M / 128, 3), 256, 0, stream>>>(x, Wq, Wk, Wv, qw,
                                                            M, N, DD);
    kqf16 = (_Float16*)(abq + NABQ);
  }
  ab_proj<<<dim3(M, 4), 64, 0, stream>>>(x, Wa, ba, Wb, bb, abq);
  norm_pack<<<(BB * TT * HH) / 4, 256, 0, stream>>>(qw, kw, kqf16, abq);
  scan_kernel<<<BB * HH * 8, 256, 0, stream>>>(kqf16, vw, abq, out);
}